// Round 2
// baseline (1241.601 us; speedup 1.0000x reference)
//
#include <hip/hip_runtime.h>

typedef unsigned short u16;
typedef unsigned int   u32;
typedef __attribute__((ext_vector_type(8))) short bf16x8;
typedef __attribute__((ext_vector_type(4))) float f32x4;

#define L_SEQ 16384
#define NHEAD 16
#define CDIM  512
#define SCALE 0.17677669529663689f

#define AS1 __attribute__((address_space(1)))
#define AS3 __attribute__((address_space(3)))

__device__ __forceinline__ float bf2f(u16 v) {
    union { u32 u; float f; } x; x.u = ((u32)v) << 16; return x.f;
}
__device__ __forceinline__ u16 f2bf(float f) {
    union { u32 u; float f; } x; x.f = f;
    u32 r = x.u + 0x7fff + ((x.u >> 16) & 1);
    return (u16)(r >> 16);
}

// ---- dtype detector: f32 junk low-halves hit bf16-exponent-all-ones w/ p=1/256.
__global__ void detect_dtype_kernel(const u16* __restrict__ x, int* __restrict__ flag) {
    __shared__ int cnt;
    if (threadIdx.x == 0) cnt = 0;
    __syncthreads();
    int c = 0;
    for (int k = 0; k < 32; k++) {
        u16 v = x[2 * (threadIdx.x + 256 * k)];
        if ((v & 0x7F80) == 0x7F80) c++;
    }
    atomicAdd(&cnt, c);
    __syncthreads();
    if (threadIdx.x == 0) *flag = (cnt > 0) ? 1 : 0;
}

// ---- all weights/biases/rpb -> one contiguous bf16 segment (5 sub-ranges)
__global__ __launch_bounds__(256)
void convert_weights_kernel(const void* __restrict__ qkv_w, const void* __restrict__ proj_w,
                            const void* __restrict__ qkv_b, const void* __restrict__ proj_b,
                            const void* __restrict__ rpb, u16* __restrict__ dst,
                            const int* __restrict__ flag) {
    const int f = *flag;
    for (int i = blockIdx.x * 256 + threadIdx.x; i < 1050832; i += gridDim.x * 256) {
        const void* src; int off;
        if (i < 786432)       { src = qkv_w;  off = i; }
        else if (i < 1048576) { src = proj_w; off = i - 786432; }
        else if (i < 1050112) { src = qkv_b;  off = i - 1048576; }
        else if (i < 1050624) { src = proj_b; off = i - 1050112; }
        else                  { src = rpb;    off = i - 1050624; }
        dst[i] = f ? f2bf(((const float*)src)[off]) : ((const u16*)src)[off];
    }
}

// ---- x rows [b*L+base_c, +lch) per b -> xc[(b*lch + r)*512 + col] bf16
__global__ __launch_bounds__(256)
void convert_x_kernel(const void* __restrict__ src, u16* __restrict__ dst,
                      int base_c, int lch, const int* __restrict__ flag) {
    const int f  = *flag;
    const int i0 = (blockIdx.x * 256 + threadIdx.x) * 8;     // [0, 2*lch*512)
    const int r  = i0 >> 9;
    const int b  = (r >= lch) ? 1 : 0;
    const size_t s = (size_t)(b * L_SEQ + base_c + (r - b * lch)) * 512 + (i0 & 511);
    if (f) {
        const float* sf = (const float*)src + s;
        union { u16 o[8]; uint4 v; } pk;
        #pragma unroll
        for (int j = 0; j < 8; j++) pk.o[j] = f2bf(sf[j]);
        *(uint4*)(dst + i0) = pk.v;
    } else {
        *(uint4*)(dst + i0) = *(const uint4*)((const u16*)src + s);
    }
}

// ============ 256x256 GEMM core: A via LDS, B direct from L1/L2 ============
// 512 thr = 8 waves (2M x 4N), per-wave C = 128x64. BK=64 as two K-halves.
// LDS holds ONLY A: [2 dbuf][2 khalf][256 rows * 32 k] = 64 KiB -> 2 blocks/CU.
// B fragments load straight from global W (1.5 MB, L2-resident; wave pairs
// share fragments -> L1 hits), bypassing the LDS pipe which was the Round-1
// wall (192 KB frag reads + 64 KB writes per K-tile vs ~100 B/cy LDS BW).
// Per K-tile: {bb: 8 global dwordx4 | BAR | stage A(T+1): 4 gload_lds |
// vmcnt(8) (forces stage(T) done, leaves stage(T+1)+newest bb in flight) |
// 2x [8 ds_read_b128 af; 32 MFMA]}. One barrier + one counted vmcnt per tile.
// A swizzle identical to Round-1 (verified, 0 conflicts): staging source col
// pre-swizzled ((lane&3)^((lane>>3)&3)), read chunk quad^((r16>>1)&3).
#define GEMM256_CORE(A_PTR, W_PTR, AROW0, N0)                                           \
    __shared__ u16 lds[2][2][8192]; /* [buf][khalf][256*32] = 64 KiB */                 \
    const int tid  = threadIdx.x;                                                       \
    const int wave = tid >> 6;                                                          \
    const int lane = tid & 63;                                                          \
    const int quad = lane >> 4;                                                         \
    const int r16  = lane & 15;                                                         \
    const int wm2  = wave >> 2;                                                         \
    const int wn4  = wave & 3;                                                          \
    f32x4 acc[8][4];                                                                    \
    _Pragma("unroll")                                                                   \
    for (int i = 0; i < 8; i++)                                                         \
        _Pragma("unroll")                                                               \
        for (int j = 0; j < 4; j++) acc[i][j] = (f32x4){0.f, 0.f, 0.f, 0.f};            \
    const int lr4  = lane >> 2;                                                         \
    const int swc2 = (((lane & 3) ^ ((lane >> 3) & 3)) << 3);                           \
    const u16* gA  = (A_PTR) + (size_t)((AROW0) + wave * 16 + lr4) * 512 + swc2;        \
    const u16* gWb = (W_PTR) + (size_t)((N0) + wn4 * 64 + r16) * 512 + quad * 8;        \
    const int rsw  = (quad ^ ((r16 >> 1) & 3)) << 3;                                    \
    const int aoff = (wm2 * 128 + r16) * 32 + rsw;                                      \
    const int sdst = wave * 512; /* (wave*16 rows)*32 */                                \
    auto STAGE = [&](int P2, int KT) {                                                  \
        _Pragma("unroll")                                                               \
        for (int kh_ = 0; kh_ < 2; kh_++) {                                             \
            const u16* g_ = gA + KT * 64 + kh_ * 32;                                    \
            u16* d0_ = &lds[P2][kh_][sdst];                                             \
            __builtin_amdgcn_global_load_lds(                                           \
                (const AS1 void*)g_, (AS3 void*)d0_, 16, 0, 0);                         \
            __builtin_amdgcn_global_load_lds(                                           \
                (const AS1 void*)(g_ + (size_t)128 * 512), (AS3 void*)(d0_ + 4096),     \
                16, 0, 0);                                                              \
        }                                                                               \
    };                                                                                  \
    STAGE(0, 0);                                                                        \
    _Pragma("unroll 2")                                                                 \
    for (int T = 0; T < 8; T++) {                                                       \
        const int p = T & 1;                                                            \
        bf16x8 bb[4][2];                                                                \
        _Pragma("unroll")                                                               \
        for (int ni = 0; ni < 4; ni++)                                                  \
            _Pragma("unroll")                                                           \
            for (int ks = 0; ks < 2; ks++)                                              \
                bb[ni][ks] = *(const bf16x8*)(gWb + ni * 8192 + T * 64 + ks * 32);      \
        __builtin_amdgcn_s_barrier();                                                   \
        if (T < 7) STAGE(p ^ 1, T + 1);                                                 \
        asm volatile("s_waitcnt vmcnt(8)" ::: "memory");                                \
        __builtin_amdgcn_sched_barrier(0);                                              \
        _Pragma("unroll")                                                               \
        for (int ks = 0; ks < 2; ks++) {                                                \
            bf16x8 af[8];                                                               \
            _Pragma("unroll")                                                           \
            for (int mi = 0; mi < 8; mi++)                                              \
                af[mi] = *(const bf16x8*)&lds[p][ks][aoff + mi * 512];                  \
            __builtin_amdgcn_s_setprio(1);                                              \
            _Pragma("unroll")                                                           \
            for (int mi = 0; mi < 8; mi++)                                              \
                _Pragma("unroll")                                                       \
                for (int ni = 0; ni < 4; ni++)                                          \
                    acc[mi][ni] = __builtin_amdgcn_mfma_f32_16x16x32_bf16(              \
                        af[mi], bb[ni][ks], acc[mi][ni], 0, 0, 0);                      \
            __builtin_amdgcn_s_setprio(0);                                              \
        }                                                                               \
    }

// ---- QKV GEMM: xc[(b*lch+r),512] @ qkv_w^T -> planes [3][b*16+h][lch][32], q*SCALE
__global__ __launch_bounds__(512, 4)
void gemm_qkv_kernel(const u16* __restrict__ A, const u16* __restrict__ W,
                     const u16* __restrict__ bias, u16* __restrict__ qkv_out, int lch)
{
    const int m0l = blockIdx.x << 8;
    const int n0  = blockIdx.y << 8;
    const int b   = blockIdx.z;
    const size_t plane = (size_t)1024 * lch;       // 2*16*lch*32
    GEMM256_CORE(A, W, b * lch + m0l, n0)
    #pragma unroll
    for (int ni = 0; ni < 4; ni++) {
        const int col   = n0 + wn4 * 64 + ni * 16 + r16;
        const int which = col >> 9;
        const int rem   = col & 511;
        const int h     = rem >> 5;
        const int d     = rem & 31;
        const float bv  = bf2f(bias[col]);
        const float scl = (which == 0) ? SCALE : 1.0f;
        u16* outb = qkv_out + (size_t)which * plane +
                    ((size_t)(b * NHEAD + h) * lch) * 32 + d;
        #pragma unroll
        for (int mi = 0; mi < 8; mi++) {
            #pragma unroll
            for (int r = 0; r < 4; r++) {
                const int rrel = m0l + wm2 * 128 + mi * 16 + quad * 4 + r;
                outb[(size_t)rrel * 32] = f2bf((acc[mi][ni][r] + bv) * scl);
            }
        }
    }
}

// ---- attention: 4 lanes per (b,h,l); each lane owns 8 bf16 (one uint4)
__global__ __launch_bounds__(256)
void attn_kernel(const uint4* __restrict__ q, const uint4* __restrict__ k,
                 const uint4* __restrict__ v, const u16* __restrict__ rpb,
                 uint4* __restrict__ outa, int c0, int base_c, int lc_shift, int lch)
{
    const int grp = blockIdx.x * 64 + (threadIdx.x >> 2);
    const int d4  = threadIdx.x & 3;
    const int lr  = grp & ((1 << lc_shift) - 1);
    const int bh  = grp >> lc_shift;                // b*16 + h
    const int h   = bh & 15;
    const int l   = c0 + lr;
    const size_t base = (size_t)bh * lch * 4;       // uint4 per row = 4

    const uint4 qp = q[base + (size_t)(l - base_c) * 4 + d4];
    float qf[8];
    qf[0] = bf2f((u16)qp.x); qf[1] = bf2f((u16)(qp.x >> 16));
    qf[2] = bf2f((u16)qp.y); qf[3] = bf2f((u16)(qp.y >> 16));
    qf[4] = bf2f((u16)qp.z); qf[5] = bf2f((u16)(qp.z >> 16));
    qf[6] = bf2f((u16)qp.w); qf[7] = bf2f((u16)(qp.w >> 16));

    int ni = l - 3;
    if (ni < 0) ni = 0;
    if (ni > L_SEQ - 7) ni = L_SEQ - 7;
    const int rn = ni - base_c;

    float logit[7];
    #pragma unroll
    for (int j = 0; j < 7; j++) {
        const uint4 kp = k[base + (size_t)(rn + j) * 4 + d4];
        float p;
        p  = qf[0] * bf2f((u16)kp.x) + qf[1] * bf2f((u16)(kp.x >> 16));
        p += qf[2] * bf2f((u16)kp.y) + qf[3] * bf2f((u16)(kp.y >> 16));
        p += qf[4] * bf2f((u16)kp.z) + qf[5] * bf2f((u16)(kp.z >> 16));
        p += qf[6] * bf2f((u16)kp.w) + qf[7] * bf2f((u16)(kp.w >> 16));
        p += __shfl_xor(p, 1, 64);
        p += __shfl_xor(p, 2, 64);
        logit[j] = p + bf2f(rpb[h * 13 + (ni + j - l + 6)]);
    }
    float mx = logit[0];
    #pragma unroll
    for (int j = 1; j < 7; j++) mx = fmaxf(mx, logit[j]);
    float s = 0.f, w[7];
    #pragma unroll
    for (int j = 0; j < 7; j++) { w[j] = __expf(logit[j] - mx); s += w[j]; }
    const float inv = 1.0f / s;
    float o[8] = {0.f, 0.f, 0.f, 0.f, 0.f, 0.f, 0.f, 0.f};
    #pragma unroll
    for (int j = 0; j < 7; j++) {
        const uint4 vp = v[base + (size_t)(rn + j) * 4 + d4];
        o[0] += w[j] * bf2f((u16)vp.x); o[1] += w[j] * bf2f((u16)(vp.x >> 16));
        o[2] += w[j] * bf2f((u16)vp.y); o[3] += w[j] * bf2f((u16)(vp.y >> 16));
        o[4] += w[j] * bf2f((u16)vp.z); o[5] += w[j] * bf2f((u16)(vp.z >> 16));
        o[6] += w[j] * bf2f((u16)vp.w); o[7] += w[j] * bf2f((u16)(vp.w >> 16));
    }
    uint4 pk;
    pk.x = (u32)f2bf(o[0] * inv) | ((u32)f2bf(o[1] * inv) << 16);
    pk.y = (u32)f2bf(o[2] * inv) | ((u32)f2bf(o[3] * inv) << 16);
    pk.z = (u32)f2bf(o[4] * inv) | ((u32)f2bf(o[5] * inv) << 16);
    pk.w = (u32)f2bf(o[6] * inv) | ((u32)f2bf(o[7] * inv) << 16);
    outa[((size_t)(((bh >> 4) << lc_shift) + lr)) * 64 + h * 4 + d4] = pk;
}

// ---- proj GEMM: wsa[(b*lc+lr),512] @ proj_w^T -> out rows b*L + c0 + lr
__global__ __launch_bounds__(512, 4)
void gemm_proj_kernel(const u16* __restrict__ A, const u16* __restrict__ W,
                      const u16* __restrict__ bias, void* __restrict__ out,
                      int c0, int lc, const int* __restrict__ flag)
{
    const int m0l = blockIdx.x << 8;
    const int n0  = blockIdx.y << 8;
    const int b   = blockIdx.z;
    GEMM256_CORE(A, W, b * lc + m0l, n0)
    const int f = *flag;
    #pragma unroll
    for (int ni = 0; ni < 4; ni++) {
        const int col  = n0 + wn4 * 64 + ni * 16 + r16;
        const float bv = bf2f(bias[col]);
        #pragma unroll
        for (int mi = 0; mi < 8; mi++) {
            #pragma unroll
            for (int r = 0; r < 4; r++) {
                const int lr = m0l + wm2 * 128 + mi * 16 + quad * 4 + r;
                const size_t idx = (size_t)(b * L_SEQ + c0 + lr) * CDIM + col;
                const float val = acc[mi][ni][r] + bv;
                if (f) ((float*)out)[idx] = val;
                else   ((u16*)out)[idx]   = f2bf(val);
            }
        }
    }
}

extern "C" void kernel_launch(void* const* d_in, const int* in_sizes, int n_in,
                              void* d_out, int out_size, void* d_ws, size_t ws_size,
                              hipStream_t stream) {
    const void* x      = d_in[0];
    const void* qkv_w  = d_in[1];
    const void* qkv_b  = d_in[2];
    const void* rpb    = d_in[3];
    const void* proj_w = d_in[4];
    const void* proj_b = d_in[5];

    // ---- chunk config chosen by ws_size (constant across calls -> graph-safe)
    // lch must be a multiple of 256 (BM) for the 256^2 GEMM core.
    int nchunk, lch, lc, lc_shift;
    static const int c0sA[1] = {0},                 basesA[1] = {0};
    static const int c0sB[2] = {0, 8192},           basesB[2] = {0, 7936};
    static const int c0sC[8] = {0, 2048, 4096, 6144, 8192, 10240, 12288, 14336};
    static const int basesC[8] = {0, 1920, 3968, 6016, 8064, 10112, 12160, 14080};
    const int* c0s; const int* bases;
    if (ws_size >= (size_t)2 * (16 + 1050880 + (size_t)4096 * 16384 + 1024 * 16384)) {
        nchunk = 1; lch = 16384; lc = 16384; lc_shift = 14; c0s = c0sA; bases = basesA;
    } else if (ws_size >= (size_t)2 * (16 + 1050880 + (size_t)4096 * 8448 + 1024 * 8192)) {
        nchunk = 2; lch = 8448;  lc = 8192;  lc_shift = 13; c0s = c0sB; bases = basesB;
    } else {
        nchunk = 8; lch = 2304;  lc = 2048;  lc_shift = 11; c0s = c0sC; bases = basesC;
    }

    u16* ws    = (u16*)d_ws;
    int* flag  = (int*)ws;                           // 16 u16
    u16* wseg  = ws + 16;                            // wqkv|wproj|bqkv|bproj|rpbc
    u16* wqkv  = wseg;
    u16* wproj = wseg + 786432;
    u16* bqkv  = wseg + 1048576;
    u16* bproj = wseg + 1050112;
    u16* rpbc  = wseg + 1050624;
    u16* xc    = ws + 16 + 1050880;                  // 2*lch*512
    u16* qkv   = xc + (size_t)1024 * lch;            // 3 planes of 1024*lch
    u16* wsa   = qkv + (size_t)3072 * lch;           // 2*lc*512

    detect_dtype_kernel<<<1, 256, 0, stream>>>((const u16*)x, flag);
    convert_weights_kernel<<<2048, 256, 0, stream>>>(qkv_w, proj_w, qkv_b, proj_b,
                                                     rpb, wseg, flag);

    for (int c = 0; c < nchunk; c++) {
        convert_x_kernel<<<lch / 2, 256, 0, stream>>>(x, xc, bases[c], lch, flag);
        gemm_qkv_kernel<<<dim3(lch / 256, 6, 2), 512, 0, stream>>>(
            xc, wqkv, bqkv, qkv, lch);
        attn_kernel<<<lc / 2, 256, 0, stream>>>(
            (const uint4*)qkv, (const uint4*)(qkv + (size_t)1024 * lch),
            (const uint4*)(qkv + (size_t)2048 * lch), rpbc,
            (uint4*)wsa, c0s[c], bases[c], lc_shift, lch);
        gemm_proj_kernel<<<dim3(lc / 256, 2, 2), 512, 0, stream>>>(
            wsa, wproj, bproj, d_out, c0s[c], lc, flag);
    }
}

// Round 3
// 310.007 us; speedup vs baseline: 4.0051x; 4.0051x over previous
//
#include <hip/hip_runtime.h>

typedef unsigned short u16;
typedef unsigned int   u32;
typedef __attribute__((ext_vector_type(8))) short bf16x8;
typedef __attribute__((ext_vector_type(4))) float f32x4;

#define L_SEQ 16384
#define NHEAD 16
#define CDIM  512
#define SCALE 0.17677669529663689f

#define AS1 __attribute__((address_space(1)))
#define AS3 __attribute__((address_space(3)))

__device__ __forceinline__ float bf2f(u16 v) {
    union { u32 u; float f; } x; x.u = ((u32)v) << 16; return x.f;
}
__device__ __forceinline__ u16 f2bf(float f) {
    union { u32 u; float f; } x; x.f = f;
    u32 r = x.u + 0x7fff + ((x.u >> 16) & 1);
    return (u16)(r >> 16);
}

// ---- dtype detector: f32 junk low-halves hit bf16-exponent-all-ones w/ p=1/256.
__global__ void detect_dtype_kernel(const u16* __restrict__ x, int* __restrict__ flag) {
    __shared__ int cnt;
    if (threadIdx.x == 0) cnt = 0;
    __syncthreads();
    int c = 0;
    for (int k = 0; k < 32; k++) {
        u16 v = x[2 * (threadIdx.x + 256 * k)];
        if ((v & 0x7F80) == 0x7F80) c++;
    }
    atomicAdd(&cnt, c);
    __syncthreads();
    if (threadIdx.x == 0) *flag = (cnt > 0) ? 1 : 0;
}

// ---- all weights/biases/rpb -> one contiguous bf16 segment (5 sub-ranges)
__global__ __launch_bounds__(256)
void convert_weights_kernel(const void* __restrict__ qkv_w, const void* __restrict__ proj_w,
                            const void* __restrict__ qkv_b, const void* __restrict__ proj_b,
                            const void* __restrict__ rpb, u16* __restrict__ dst,
                            const int* __restrict__ flag) {
    const int f = *flag;
    for (int i = blockIdx.x * 256 + threadIdx.x; i < 1050832; i += gridDim.x * 256) {
        const void* src; int off;
        if (i < 786432)       { src = qkv_w;  off = i; }
        else if (i < 1048576) { src = proj_w; off = i - 786432; }
        else if (i < 1050112) { src = qkv_b;  off = i - 1048576; }
        else if (i < 1050624) { src = proj_b; off = i - 1050112; }
        else                  { src = rpb;    off = i - 1050624; }
        dst[i] = f ? f2bf(((const float*)src)[off]) : ((const u16*)src)[off];
    }
}

// ---- x rows [b*L+base_c, +lch) per b -> xc[(b*lch + r)*512 + col] bf16
__global__ __launch_bounds__(256)
void convert_x_kernel(const void* __restrict__ src, u16* __restrict__ dst,
                      int base_c, int lch, const int* __restrict__ flag) {
    const int f  = *flag;
    const int i0 = (blockIdx.x * 256 + threadIdx.x) * 8;     // [0, 2*lch*512)
    const int r  = i0 >> 9;
    const int b  = (r >= lch) ? 1 : 0;
    const size_t s = (size_t)(b * L_SEQ + base_c + (r - b * lch)) * 512 + (i0 & 511);
    if (f) {
        const float* sf = (const float*)src + s;
        union { u16 o[8]; uint4 v; } pk;
        #pragma unroll
        for (int j = 0; j < 8; j++) pk.o[j] = f2bf(sf[j]);
        *(uint4*)(dst + i0) = pk.v;
    } else {
        *(uint4*)(dst + i0) = *(const uint4*)((const u16*)src + s);
    }
}

// ============ 256x256 GEMM core: A via LDS, B direct from L1/L2 ============
// 512 thr = 8 waves (2M x 4N), per-wave C = 128x64. BK=64 as two K-halves.
// LDS holds ONLY A: [2 dbuf][2 khalf][256 rows * 32 k] = 64 KiB.
// B fragments load straight from global W (1.5 MB, L2-resident; wave pairs
// share fragments -> L1 hits), bypassing the LDS pipe (Round-1 wall: 192 KB
// frag reads + 64 KB writes per K-tile vs ~100 B/cy LDS BW).
// Per K-tile: {bb: 8 global dwordx4 | BAR | stage A(T+1): 4 gload_lds |
// vmcnt(8) (forces stage(T) done, leaves stage(T+1)+newest bb in flight) |
// 2x [8 ds_read_b128 af; 32 MFMA]}. One barrier + one counted vmcnt per tile.
// A swizzle (verified, 0 conflicts): staging source col pre-swizzled
// ((lane&3)^((lane>>3)&3)), read chunk quad^((r16>>1)&3).
// NOTE launch_bounds: 2nd arg is MIN WAVES PER EU. (512,4) caps VGPR at 128
// -> acc[8][4] spills (Round-2: 2.2 GB scratch writes, VGPR=64, 10x slowdown).
// (512,2) caps at 256; acc+frags+addr ~ 220 fits.
#define GEMM256_CORE(A_PTR, W_PTR, AROW0, N0)                                           \
    __shared__ u16 lds[2][2][8192]; /* [buf][khalf][256*32] = 64 KiB */                 \
    const int tid  = threadIdx.x;                                                       \
    const int wave = tid >> 6;                                                          \
    const int lane = tid & 63;                                                          \
    const int quad = lane >> 4;                                                         \
    const int r16  = lane & 15;                                                         \
    const int wm2  = wave >> 2;                                                         \
    const int wn4  = wave & 3;                                                          \
    f32x4 acc[8][4];                                                                    \
    _Pragma("unroll")                                                                   \
    for (int i = 0; i < 8; i++)                                                         \
        _Pragma("unroll")                                                               \
        for (int j = 0; j < 4; j++) acc[i][j] = (f32x4){0.f, 0.f, 0.f, 0.f};            \
    const int lr4  = lane >> 2;                                                         \
    const int swc2 = (((lane & 3) ^ ((lane >> 3) & 3)) << 3);                           \
    const u16* gA  = (A_PTR) + (size_t)((AROW0) + wave * 16 + lr4) * 512 + swc2;        \
    const u16* gWb = (W_PTR) + (size_t)((N0) + wn4 * 64 + r16) * 512 + quad * 8;        \
    const int rsw  = (quad ^ ((r16 >> 1) & 3)) << 3;                                    \
    const int aoff = (wm2 * 128 + r16) * 32 + rsw;                                      \
    const int sdst = wave * 512; /* (wave*16 rows)*32 */                                \
    auto STAGE = [&](int P2, int KT) {                                                  \
        _Pragma("unroll")                                                               \
        for (int kh_ = 0; kh_ < 2; kh_++) {                                             \
            const u16* g_ = gA + KT * 64 + kh_ * 32;                                    \
            u16* d0_ = &lds[P2][kh_][sdst];                                             \
            __builtin_amdgcn_global_load_lds(                                           \
                (const AS1 void*)g_, (AS3 void*)d0_, 16, 0, 0);                         \
            __builtin_amdgcn_global_load_lds(                                           \
                (const AS1 void*)(g_ + (size_t)128 * 512), (AS3 void*)(d0_ + 4096),     \
                16, 0, 0);                                                              \
        }                                                                               \
    };                                                                                  \
    STAGE(0, 0);                                                                        \
    _Pragma("unroll 2")                                                                 \
    for (int T = 0; T < 8; T++) {                                                       \
        const int p = T & 1;                                                            \
        bf16x8 bb[4][2];                                                                \
        _Pragma("unroll")                                                               \
        for (int ni = 0; ni < 4; ni++)                                                  \
            _Pragma("unroll")                                                           \
            for (int ks = 0; ks < 2; ks++)                                              \
                bb[ni][ks] = *(const bf16x8*)(gWb + ni * 8192 + T * 64 + ks * 32);      \
        __builtin_amdgcn_s_barrier();                                                   \
        if (T < 7) STAGE(p ^ 1, T + 1);                                                 \
        asm volatile("s_waitcnt vmcnt(8)" ::: "memory");                                \
        __builtin_amdgcn_sched_barrier(0);                                              \
        _Pragma("unroll")                                                               \
        for (int ks = 0; ks < 2; ks++) {                                                \
            bf16x8 af[8];                                                               \
            _Pragma("unroll")                                                           \
            for (int mi = 0; mi < 8; mi++)                                              \
                af[mi] = *(const bf16x8*)&lds[p][ks][aoff + mi * 512];                  \
            __builtin_amdgcn_s_setprio(1);                                              \
            _Pragma("unroll")                                                           \
            for (int mi = 0; mi < 8; mi++)                                              \
                _Pragma("unroll")                                                       \
                for (int ni = 0; ni < 4; ni++)                                          \
                    acc[mi][ni] = __builtin_amdgcn_mfma_f32_16x16x32_bf16(              \
                        af[mi], bb[ni][ks], acc[mi][ni], 0, 0, 0);                      \
            __builtin_amdgcn_s_setprio(0);                                              \
        }                                                                               \
    }

// ---- QKV GEMM: xc[(b*lch+r),512] @ qkv_w^T -> planes [3][b*16+h][lch][32], q*SCALE
__global__ __launch_bounds__(512, 2)
void gemm_qkv_kernel(const u16* __restrict__ A, const u16* __restrict__ W,
                     const u16* __restrict__ bias, u16* __restrict__ qkv_out, int lch)
{
    const int m0l = blockIdx.x << 8;
    const int n0  = blockIdx.y << 8;
    const int b   = blockIdx.z;
    const size_t plane = (size_t)1024 * lch;       // 2*16*lch*32
    GEMM256_CORE(A, W, b * lch + m0l, n0)
    #pragma unroll
    for (int ni = 0; ni < 4; ni++) {
        const int col   = n0 + wn4 * 64 + ni * 16 + r16;
        const int which = col >> 9;
        const int rem   = col & 511;
        const int h     = rem >> 5;
        const int d     = rem & 31;
        const float bv  = bf2f(bias[col]);
        const float scl = (which == 0) ? SCALE : 1.0f;
        u16* outb = qkv_out + (size_t)which * plane +
                    ((size_t)(b * NHEAD + h) * lch) * 32 + d;
        #pragma unroll
        for (int mi = 0; mi < 8; mi++) {
            #pragma unroll
            for (int r = 0; r < 4; r++) {
                const int rrel = m0l + wm2 * 128 + mi * 16 + quad * 4 + r;
                outb[(size_t)rrel * 32] = f2bf((acc[mi][ni][r] + bv) * scl);
            }
        }
    }
}

// ---- attention: 4 lanes per (b,h,l); each lane owns 8 bf16 (one uint4)
__global__ __launch_bounds__(256)
void attn_kernel(const uint4* __restrict__ q, const uint4* __restrict__ k,
                 const uint4* __restrict__ v, const u16* __restrict__ rpb,
                 uint4* __restrict__ outa, int c0, int base_c, int lc_shift, int lch)
{
    const int grp = blockIdx.x * 64 + (threadIdx.x >> 2);
    const int d4  = threadIdx.x & 3;
    const int lr  = grp & ((1 << lc_shift) - 1);
    const int bh  = grp >> lc_shift;                // b*16 + h
    const int h   = bh & 15;
    const int l   = c0 + lr;
    const size_t base = (size_t)bh * lch * 4;       // uint4 per row = 4

    const uint4 qp = q[base + (size_t)(l - base_c) * 4 + d4];
    float qf[8];
    qf[0] = bf2f((u16)qp.x); qf[1] = bf2f((u16)(qp.x >> 16));
    qf[2] = bf2f((u16)qp.y); qf[3] = bf2f((u16)(qp.y >> 16));
    qf[4] = bf2f((u16)qp.z); qf[5] = bf2f((u16)(qp.z >> 16));
    qf[6] = bf2f((u16)qp.w); qf[7] = bf2f((u16)(qp.w >> 16));

    int ni = l - 3;
    if (ni < 0) ni = 0;
    if (ni > L_SEQ - 7) ni = L_SEQ - 7;
    const int rn = ni - base_c;

    float logit[7];
    #pragma unroll
    for (int j = 0; j < 7; j++) {
        const uint4 kp = k[base + (size_t)(rn + j) * 4 + d4];
        float p;
        p  = qf[0] * bf2f((u16)kp.x) + qf[1] * bf2f((u16)(kp.x >> 16));
        p += qf[2] * bf2f((u16)kp.y) + qf[3] * bf2f((u16)(kp.y >> 16));
        p += qf[4] * bf2f((u16)kp.z) + qf[5] * bf2f((u16)(kp.z >> 16));
        p += qf[6] * bf2f((u16)kp.w) + qf[7] * bf2f((u16)(kp.w >> 16));
        p += __shfl_xor(p, 1, 64);
        p += __shfl_xor(p, 2, 64);
        logit[j] = p + bf2f(rpb[h * 13 + (ni + j - l + 6)]);
    }
    float mx = logit[0];
    #pragma unroll
    for (int j = 1; j < 7; j++) mx = fmaxf(mx, logit[j]);
    float s = 0.f, w[7];
    #pragma unroll
    for (int j = 0; j < 7; j++) { w[j] = __expf(logit[j] - mx); s += w[j]; }
    const float inv = 1.0f / s;
    float o[8] = {0.f, 0.f, 0.f, 0.f, 0.f, 0.f, 0.f, 0.f};
    #pragma unroll
    for (int j = 0; j < 7; j++) {
        const uint4 vp = v[base + (size_t)(rn + j) * 4 + d4];
        o[0] += w[j] * bf2f((u16)vp.x); o[1] += w[j] * bf2f((u16)(vp.x >> 16));
        o[2] += w[j] * bf2f((u16)vp.y); o[3] += w[j] * bf2f((u16)(vp.y >> 16));
        o[4] += w[j] * bf2f((u16)vp.z); o[5] += w[j] * bf2f((u16)(vp.z >> 16));
        o[6] += w[j] * bf2f((u16)vp.w); o[7] += w[j] * bf2f((u16)(vp.w >> 16));
    }
    uint4 pk;
    pk.x = (u32)f2bf(o[0] * inv) | ((u32)f2bf(o[1] * inv) << 16);
    pk.y = (u32)f2bf(o[2] * inv) | ((u32)f2bf(o[3] * inv) << 16);
    pk.z = (u32)f2bf(o[4] * inv) | ((u32)f2bf(o[5] * inv) << 16);
    pk.w = (u32)f2bf(o[6] * inv) | ((u32)f2bf(o[7] * inv) << 16);
    outa[((size_t)(((bh >> 4) << lc_shift) + lr)) * 64 + h * 4 + d4] = pk;
}

// ---- proj GEMM: wsa[(b*lc+lr),512] @ proj_w^T -> out rows b*L + c0 + lr
__global__ __launch_bounds__(512, 2)
void gemm_proj_kernel(const u16* __restrict__ A, const u16* __restrict__ W,
                      const u16* __restrict__ bias, void* __restrict__ out,
                      int c0, int lc, const int* __restrict__ flag)
{
    const int m0l = blockIdx.x << 8;
    const int n0  = blockIdx.y << 8;
    const int b   = blockIdx.z;
    GEMM256_CORE(A, W, b * lc + m0l, n0)
    const int f = *flag;
    #pragma unroll
    for (int ni = 0; ni < 4; ni++) {
        const int col  = n0 + wn4 * 64 + ni * 16 + r16;
        const float bv = bf2f(bias[col]);
        #pragma unroll
        for (int mi = 0; mi < 8; mi++) {
            #pragma unroll
            for (int r = 0; r < 4; r++) {
                const int lr = m0l + wm2 * 128 + mi * 16 + quad * 4 + r;
                const size_t idx = (size_t)(b * L_SEQ + c0 + lr) * CDIM + col;
                const float val = acc[mi][ni][r] + bv;
                if (f) ((float*)out)[idx] = val;
                else   ((u16*)out)[idx]   = f2bf(val);
            }
        }
    }
}

extern "C" void kernel_launch(void* const* d_in, const int* in_sizes, int n_in,
                              void* d_out, int out_size, void* d_ws, size_t ws_size,
                              hipStream_t stream) {
    const void* x      = d_in[0];
    const void* qkv_w  = d_in[1];
    const void* qkv_b  = d_in[2];
    const void* rpb    = d_in[3];
    const void* proj_w = d_in[4];
    const void* proj_b = d_in[5];

    // ---- chunk config chosen by ws_size (constant across calls -> graph-safe)
    // lch must be a multiple of 256 (BM) for the 256^2 GEMM core.
    int nchunk, lch, lc, lc_shift;
    static const int c0sA[1] = {0},                 basesA[1] = {0};
    static const int c0sB[2] = {0, 8192},           basesB[2] = {0, 7936};
    static const int c0sC[8] = {0, 2048, 4096, 6144, 8192, 10240, 12288, 14336};
    static const int basesC[8] = {0, 1920, 3968, 6016, 8064, 10112, 12160, 14080};
    const int* c0s; const int* bases;
    if (ws_size >= (size_t)2 * (16 + 1050880 + (size_t)4096 * 16384 + 1024 * 16384)) {
        nchunk = 1; lch = 16384; lc = 16384; lc_shift = 14; c0s = c0sA; bases = basesA;
    } else if (ws_size >= (size_t)2 * (16 + 1050880 + (size_t)4096 * 8448 + 1024 * 8192)) {
        nchunk = 2; lch = 8448;  lc = 8192;  lc_shift = 13; c0s = c0sB; bases = basesB;
    } else {
        nchunk = 8; lch = 2304;  lc = 2048;  lc_shift = 11; c0s = c0sC; bases = basesC;
    }

    u16* ws    = (u16*)d_ws;
    int* flag  = (int*)ws;                           // 16 u16
    u16* wseg  = ws + 16;                            // wqkv|wproj|bqkv|bproj|rpbc
    u16* wqkv  = wseg;
    u16* wproj = wseg + 786432;
    u16* bqkv  = wseg + 1048576;
    u16* bproj = wseg + 1050112;
    u16* rpbc  = wseg + 1050624;
    u16* xc    = ws + 16 + 1050880;                  // 2*lch*512
    u16* qkv   = xc + (size_t)1024 * lch;            // 3 planes of 1024*lch
    u16* wsa   = qkv + (size_t)3072 * lch;           // 2*lc*512

    detect_dtype_kernel<<<1, 256, 0, stream>>>((const u16*)x, flag);
    convert_weights_kernel<<<2048, 256, 0, stream>>>(qkv_w, proj_w, qkv_b, proj_b,
                                                     rpb, wseg, flag);

    for (int c = 0; c < nchunk; c++) {
        convert_x_kernel<<<lch / 2, 256, 0, stream>>>(x, xc, bases[c], lch, flag);
        gemm_qkv_kernel<<<dim3(lch / 256, 6, 2), 512, 0, stream>>>(
            xc, wqkv, bqkv, qkv, lch);
        attn_kernel<<<lc / 2, 256, 0, stream>>>(
            (const uint4*)qkv, (const uint4*)(qkv + (size_t)1024 * lch),
            (const uint4*)(qkv + (size_t)2048 * lch), rpbc,
            (uint4*)wsa, c0s[c], bases[c], lc_shift, lch);
        gemm_proj_kernel<<<dim3(lc / 256, 2, 2), 512, 0, stream>>>(
            wsa, wproj, bproj, d_out, c0s[c], lc, flag);
    }
}

// Round 4
// 279.790 us; speedup vs baseline: 4.4376x; 1.1080x over previous
//
#include <hip/hip_runtime.h>

typedef unsigned short u16;
typedef unsigned int   u32;
typedef __attribute__((ext_vector_type(8))) short bf16x8;
typedef __attribute__((ext_vector_type(4))) float f32x4;

#define L_SEQ 16384
#define NHEAD 16
#define CDIM  512
#define SCALE 0.17677669529663689f

#define AS1 __attribute__((address_space(1)))
#define AS3 __attribute__((address_space(3)))

__device__ __forceinline__ float bf2f(u16 v) {
    union { u32 u; float f; } x; x.u = ((u32)v) << 16; return x.f;
}
__device__ __forceinline__ u16 f2bf(float f) {
    union { u32 u; float f; } x; x.f = f;
    u32 r = x.u + 0x7fff + ((x.u >> 16) & 1);
    return (u16)(r >> 16);
}

// ---- weights/biases/rpb -> one contiguous bf16 segment; dtype detect fused.
// Every block samples the SAME 32 KB of x (deterministic -> all blocks agree);
// block 0 publishes flag for convert_x / gemm_proj (stream-ordered).
__global__ __launch_bounds__(256)
void convert_weights_kernel(const void* __restrict__ qkv_w, const void* __restrict__ proj_w,
                            const void* __restrict__ qkv_b, const void* __restrict__ proj_b,
                            const void* __restrict__ rpb, u16* __restrict__ dst,
                            const u16* __restrict__ x, int* __restrict__ flag_out) {
    __shared__ int cnt;
    if (threadIdx.x == 0) cnt = 0;
    __syncthreads();
    int c = 0;
    for (int k = 0; k < 32; k++) {
        u16 v = x[2 * (threadIdx.x + 256 * k)];
        if ((v & 0x7F80) == 0x7F80) c++;
    }
    atomicAdd(&cnt, c);
    __syncthreads();
    const int f = (cnt > 0) ? 1 : 0;
    if (blockIdx.x == 0 && threadIdx.x == 0) *flag_out = f;
    for (int i = blockIdx.x * 256 + threadIdx.x; i < 1050832; i += gridDim.x * 256) {
        const void* src; int off;
        if (i < 786432)       { src = qkv_w;  off = i; }
        else if (i < 1048576) { src = proj_w; off = i - 786432; }
        else if (i < 1050112) { src = qkv_b;  off = i - 1048576; }
        else if (i < 1050624) { src = proj_b; off = i - 1050112; }
        else                  { src = rpb;    off = i - 1050624; }
        dst[i] = f ? f2bf(((const float*)src)[off]) : ((const u16*)src)[off];
    }
}

// ---- x rows [b*L+base_c, +lch) per b -> xc[(b*lch + r)*512 + col] bf16
__global__ __launch_bounds__(256)
void convert_x_kernel(const void* __restrict__ src, u16* __restrict__ dst,
                      int base_c, int lch, const int* __restrict__ flag) {
    const int f  = *flag;
    const int i0 = (blockIdx.x * 256 + threadIdx.x) * 8;     // [0, 2*lch*512)
    const int r  = i0 >> 9;
    const int b  = (r >= lch) ? 1 : 0;
    const size_t s = (size_t)(b * L_SEQ + base_c + (r - b * lch)) * 512 + (i0 & 511);
    if (f) {
        const float* sf = (const float*)src + s;
        union { u16 o[8]; uint4 v; } pk;
        #pragma unroll
        for (int j = 0; j < 8; j++) pk.o[j] = f2bf(sf[j]);
        *(uint4*)(dst + i0) = pk.v;
    } else {
        *(uint4*)(dst + i0) = *(const uint4*)((const u16*)src + s);
    }
}

// ===== 256x256 8-phase GEMM core (Round-1 proven schedule, 80 us) =====
// 512 thr = 8 waves (2M x 4N), per-wave C = 128x64. BK=64 as two K-halves.
// LDS [2 dbuf][A,B][2 khalf][256 rows][32 k] = 128 KiB.
// Per K-tile: 4 phases (ks,ch): {ds_read frags | stage 1 half-tile |
// counted vmcnt | barrier | lgkmcnt(0) | setprio(1) 16 MFMA | setprio(0) |
// barrier}. vmcnt(4) at phases 2,4 only; never 0 in main loop.
// MFMA operands SWAPPED vs Round-1: mfma(bb, af, acc) -> per-lane acc holds
// 4 consecutive OUTPUT COLUMNS (row = r16, col = quad*4+r within 16x16 tile),
// enabling 8B/16B epilogue stores instead of 128 scalar 2B stores per lane.
#define VM4   asm volatile("s_waitcnt vmcnt(4)" ::: "memory")
#define VM0   asm volatile("s_waitcnt vmcnt(0)" ::: "memory")
#define LGKM0 asm volatile("s_waitcnt lgkmcnt(0)" ::: "memory")
#define NOOP  ((void)0)

#define PHASE(P, KS, CH, STAGE_STMT, WAIT_STMT)                                         \
    {                                                                                   \
        if ((CH) == 0) {                                                                \
            _Pragma("unroll")                                                           \
            for (int i_ = 0; i_ < 4; i_++)                                              \
                bb[i_] = *(const bf16x8*)&lds[P][1][KS][boff + i_ * 512];               \
        }                                                                               \
        _Pragma("unroll")                                                               \
        for (int i_ = 0; i_ < 4; i_++)                                                  \
            af[i_] = *(const bf16x8*)&lds[P][0][KS][aoff + ((CH) * 4 + i_) * 512];      \
        STAGE_STMT;                                                                     \
        WAIT_STMT;                                                                      \
        __builtin_amdgcn_s_barrier();                                                   \
        LGKM0;                                                                          \
        __builtin_amdgcn_s_setprio(1);                                                  \
        _Pragma("unroll")                                                               \
        for (int mi_ = 0; mi_ < 4; mi_++)                                               \
            _Pragma("unroll")                                                           \
            for (int ni_ = 0; ni_ < 4; ni_++)                                           \
                acc[(CH) * 4 + mi_][ni_] = __builtin_amdgcn_mfma_f32_16x16x32_bf16(     \
                    bb[ni_], af[mi_], acc[(CH) * 4 + mi_][ni_], 0, 0, 0);               \
        __builtin_amdgcn_s_setprio(0);                                                  \
        __builtin_amdgcn_s_barrier();                                                   \
    }

#define GEMM256_CORE(A_PTR, W_PTR, AROW0, N0)                                           \
    __shared__ u16 lds[2][2][2][8192]; /* [buf][op A=0/B=1][khalf][256*32] */           \
    const int tid  = threadIdx.x;                                                       \
    const int wave = tid >> 6;                                                          \
    const int lane = tid & 63;                                                          \
    const int quad = lane >> 4;                                                         \
    const int r16  = lane & 15;                                                         \
    const int wm2  = wave >> 2;                                                         \
    const int wn4  = wave & 3;                                                          \
    f32x4 acc[8][4];                                                                    \
    _Pragma("unroll")                                                                   \
    for (int i = 0; i < 8; i++)                                                         \
        _Pragma("unroll")                                                               \
        for (int j = 0; j < 4; j++) acc[i][j] = (f32x4){0.f, 0.f, 0.f, 0.f};            \
    const int lr4  = lane >> 2;                                                         \
    const int swc2 = (((lane & 3) ^ ((lane >> 3) & 3)) << 3);                           \
    const u16* gA = (A_PTR) + (size_t)((AROW0) + wave * 16 + lr4) * 512 + swc2;         \
    const u16* gW = (W_PTR) + (size_t)((N0)    + wave * 16 + lr4) * 512 + swc2;         \
    const int rsw  = (quad ^ ((r16 >> 1) & 3)) << 3;                                    \
    const int aoff = (wm2 * 128 + r16) * 32 + rsw;                                      \
    const int boff = (wn4 * 64  + r16) * 32 + rsw;                                      \
    const int sdst = wave * 512; /* (wave*16 rows)*32 */                                \
    bf16x8 af[4], bb[4];                                                                \
    auto STAGE = [&](int P2, int OP, int KT, int KS) {                                  \
        const u16* g = (OP ? gW : gA) + KT * 64 + KS * 32;                              \
        u16* d0 = &lds[P2][OP][KS][sdst];                                               \
        __builtin_amdgcn_global_load_lds(                                               \
            (const AS1 void*)g, (AS3 void*)d0, 16, 0, 0);                               \
        __builtin_amdgcn_global_load_lds(                                               \
            (const AS1 void*)(g + (size_t)128 * 512), (AS3 void*)(d0 + 4096),           \
            16, 0, 0);                                                                  \
    };                                                                                  \
    STAGE(0, 0, 0, 0); STAGE(0, 1, 0, 0); STAGE(0, 0, 0, 1); STAGE(0, 1, 0, 1);         \
    VM4;                                                                                \
    __builtin_amdgcn_s_barrier();                                                       \
    for (int T = 0; T < 7; T++) {                                                       \
        const int p = T & 1, pn = p ^ 1;                                                \
        PHASE(p, 0, 0, STAGE(pn, 0, T + 1, 0), NOOP);                                   \
        PHASE(p, 0, 1, STAGE(pn, 1, T + 1, 0), VM4);                                    \
        PHASE(p, 1, 0, STAGE(pn, 0, T + 1, 1), NOOP);                                   \
        PHASE(p, 1, 1, STAGE(pn, 1, T + 1, 1), VM4);                                    \
    }                                                                                   \
    PHASE(1, 0, 0, NOOP, NOOP);                                                         \
    PHASE(1, 0, 1, NOOP, VM0);                                                          \
    PHASE(1, 1, 0, NOOP, NOOP);                                                         \
    PHASE(1, 1, 1, NOOP, NOOP);

// ---- QKV GEMM: xc[(b*lch+r),512] @ qkv_w^T -> planes [3][b*16+h][lch][32], q*SCALE
__global__ __launch_bounds__(512, 2)
void gemm_qkv_kernel(const u16* __restrict__ A, const u16* __restrict__ W,
                     const u16* __restrict__ bias, u16* __restrict__ qkv_out, int lch)
{
    const int m0l = blockIdx.x << 8;
    const int n0  = blockIdx.y << 8;
    const int b   = blockIdx.z;
    const size_t plane = (size_t)1024 * lch;       // 2*16*lch*32
    GEMM256_CORE(A, W, b * lch + m0l, n0)
    // swapped layout: per lane, tile (i,ni) holds row r16, cols quad*4 + 0..3
    #pragma unroll
    for (int ni = 0; ni < 4; ni++) {
        const int colb  = n0 + wn4 * 64 + ni * 16 + quad * 4;
        const int which = colb >> 9;
        const int rem   = colb & 511;
        const int h     = rem >> 5;
        const int d     = rem & 31;                // 4-aligned -> 8B-aligned store
        const float scl = (which == 0) ? SCALE : 1.0f;
        const uint2 bp  = *(const uint2*)(bias + colb);
        const float b0 = bf2f((u16)bp.x), b1 = bf2f((u16)(bp.x >> 16));
        const float b2 = bf2f((u16)bp.y), b3 = bf2f((u16)(bp.y >> 16));
        u16* outb = qkv_out + (size_t)which * plane +
                    (size_t)(b * NHEAD + h) * lch * 32 + d;
        #pragma unroll
        for (int i = 0; i < 8; i++) {
            const int rrel = m0l + wm2 * 128 + i * 16 + r16;
            uint2 pk2;
            pk2.x = (u32)f2bf((acc[i][ni][0] + b0) * scl) |
                    ((u32)f2bf((acc[i][ni][1] + b1) * scl) << 16);
            pk2.y = (u32)f2bf((acc[i][ni][2] + b2) * scl) |
                    ((u32)f2bf((acc[i][ni][3] + b3) * scl) << 16);
            *(uint2*)(outb + (size_t)rrel * 32) = pk2;
        }
    }
}

// ---- attention: 4 lanes per (b,h,l); each lane owns 8 bf16 (one uint4)
__global__ __launch_bounds__(256)
void attn_kernel(const uint4* __restrict__ q, const uint4* __restrict__ k,
                 const uint4* __restrict__ v, const u16* __restrict__ rpb,
                 uint4* __restrict__ outa, int c0, int base_c, int lc_shift, int lch)
{
    const int grp = blockIdx.x * 64 + (threadIdx.x >> 2);
    const int d4  = threadIdx.x & 3;
    const int lr  = grp & ((1 << lc_shift) - 1);
    const int bh  = grp >> lc_shift;                // b*16 + h
    const int h   = bh & 15;
    const int l   = c0 + lr;
    const size_t base = (size_t)bh * lch * 4;       // uint4 per row = 4

    const uint4 qp = q[base + (size_t)(l - base_c) * 4 + d4];
    float qf[8];
    qf[0] = bf2f((u16)qp.x); qf[1] = bf2f((u16)(qp.x >> 16));
    qf[2] = bf2f((u16)qp.y); qf[3] = bf2f((u16)(qp.y >> 16));
    qf[4] = bf2f((u16)qp.z); qf[5] = bf2f((u16)(qp.z >> 16));
    qf[6] = bf2f((u16)qp.w); qf[7] = bf2f((u16)(qp.w >> 16));

    int ni = l - 3;
    if (ni < 0) ni = 0;
    if (ni > L_SEQ - 7) ni = L_SEQ - 7;
    const int rn = ni - base_c;

    float logit[7];
    #pragma unroll
    for (int j = 0; j < 7; j++) {
        const uint4 kp = k[base + (size_t)(rn + j) * 4 + d4];
        float p;
        p  = qf[0] * bf2f((u16)kp.x) + qf[1] * bf2f((u16)(kp.x >> 16));
        p += qf[2] * bf2f((u16)kp.y) + qf[3] * bf2f((u16)(kp.y >> 16));
        p += qf[4] * bf2f((u16)kp.z) + qf[5] * bf2f((u16)(kp.z >> 16));
        p += qf[6] * bf2f((u16)kp.w) + qf[7] * bf2f((u16)(kp.w >> 16));
        p += __shfl_xor(p, 1, 64);
        p += __shfl_xor(p, 2, 64);
        logit[j] = p + bf2f(rpb[h * 13 + (ni + j - l + 6)]);
    }
    float mx = logit[0];
    #pragma unroll
    for (int j = 1; j < 7; j++) mx = fmaxf(mx, logit[j]);
    float s = 0.f, w[7];
    #pragma unroll
    for (int j = 0; j < 7; j++) { w[j] = __expf(logit[j] - mx); s += w[j]; }
    const float inv = 1.0f / s;
    float o[8] = {0.f, 0.f, 0.f, 0.f, 0.f, 0.f, 0.f, 0.f};
    #pragma unroll
    for (int j = 0; j < 7; j++) {
        const uint4 vp = v[base + (size_t)(rn + j) * 4 + d4];
        o[0] += w[j] * bf2f((u16)vp.x); o[1] += w[j] * bf2f((u16)(vp.x >> 16));
        o[2] += w[j] * bf2f((u16)vp.y); o[3] += w[j] * bf2f((u16)(vp.y >> 16));
        o[4] += w[j] * bf2f((u16)vp.z); o[5] += w[j] * bf2f((u16)(vp.z >> 16));
        o[6] += w[j] * bf2f((u16)vp.w); o[7] += w[j] * bf2f((u16)(vp.w >> 16));
    }
    uint4 pk;
    pk.x = (u32)f2bf(o[0] * inv) | ((u32)f2bf(o[1] * inv) << 16);
    pk.y = (u32)f2bf(o[2] * inv) | ((u32)f2bf(o[3] * inv) << 16);
    pk.z = (u32)f2bf(o[4] * inv) | ((u32)f2bf(o[5] * inv) << 16);
    pk.w = (u32)f2bf(o[6] * inv) | ((u32)f2bf(o[7] * inv) << 16);
    outa[((size_t)(((bh >> 4) << lc_shift) + lr)) * 64 + h * 4 + d4] = pk;
}

// ---- proj GEMM: wsa[(b*lc+lr),512] @ proj_w^T -> out rows b*L + c0 + lr
__global__ __launch_bounds__(512, 2)
void gemm_proj_kernel(const u16* __restrict__ A, const u16* __restrict__ W,
                      const u16* __restrict__ bias, void* __restrict__ out,
                      int c0, int lc, const int* __restrict__ flag)
{
    const int m0l = blockIdx.x << 8;
    const int n0  = blockIdx.y << 8;
    const int b   = blockIdx.z;
    GEMM256_CORE(A, W, b * lc + m0l, n0)
    const int f = *flag;
    #pragma unroll
    for (int ni = 0; ni < 4; ni++) {
        const int colb = n0 + wn4 * 64 + ni * 16 + quad * 4; // 4-aligned
        const uint2 bp = *(const uint2*)(bias + colb);
        const float b0 = bf2f((u16)bp.x), b1 = bf2f((u16)(bp.x >> 16));
        const float b2 = bf2f((u16)bp.y), b3 = bf2f((u16)(bp.y >> 16));
        #pragma unroll
        for (int i = 0; i < 8; i++) {
            const int lr = m0l + wm2 * 128 + i * 16 + r16;
            const size_t idx = (size_t)(b * L_SEQ + c0 + lr) * CDIM + colb;
            const float v0 = acc[i][ni][0] + b0, v1 = acc[i][ni][1] + b1;
            const float v2 = acc[i][ni][2] + b2, v3 = acc[i][ni][3] + b3;
            if (f) {
                float4 st; st.x = v0; st.y = v1; st.z = v2; st.w = v3;
                *(float4*)((float*)out + idx) = st;   // 16B-aligned (colb%4==0)
            } else {
                uint2 pk2;
                pk2.x = (u32)f2bf(v0) | ((u32)f2bf(v1) << 16);
                pk2.y = (u32)f2bf(v2) | ((u32)f2bf(v3) << 16);
                *(uint2*)((u16*)out + idx) = pk2;
            }
        }
    }
}

extern "C" void kernel_launch(void* const* d_in, const int* in_sizes, int n_in,
                              void* d_out, int out_size, void* d_ws, size_t ws_size,
                              hipStream_t stream) {
    const void* x      = d_in[0];
    const void* qkv_w  = d_in[1];
    const void* qkv_b  = d_in[2];
    const void* rpb    = d_in[3];
    const void* proj_w = d_in[4];
    const void* proj_b = d_in[5];

    // ---- chunk config chosen by ws_size (constant across calls -> graph-safe)
    // lch must be a multiple of 256 (BM) for the 256^2 GEMM core.
    int nchunk, lch, lc, lc_shift;
    static const int c0sA[1] = {0},                 basesA[1] = {0};
    static const int c0sB[2] = {0, 8192},           basesB[2] = {0, 7936};
    static const int c0sC[8] = {0, 2048, 4096, 6144, 8192, 10240, 12288, 14336};
    static const int basesC[8] = {0, 1920, 3968, 6016, 8064, 10112, 12160, 14080};
    const int* c0s; const int* bases;
    if (ws_size >= (size_t)2 * (16 + 1050880 + (size_t)4096 * 16384 + 1024 * 16384)) {
        nchunk = 1; lch = 16384; lc = 16384; lc_shift = 14; c0s = c0sA; bases = basesA;
    } else if (ws_size >= (size_t)2 * (16 + 1050880 + (size_t)4096 * 8448 + 1024 * 8192)) {
        nchunk = 2; lch = 8448;  lc = 8192;  lc_shift = 13; c0s = c0sB; bases = basesB;
    } else {
        nchunk = 8; lch = 2304;  lc = 2048;  lc_shift = 11; c0s = c0sC; bases = basesC;
    }

    u16* ws    = (u16*)d_ws;
    int* flag  = (int*)ws;                           // 16 u16
    u16* wseg  = ws + 16;                            // wqkv|wproj|bqkv|bproj|rpbc
    u16* wqkv  = wseg;
    u16* wproj = wseg + 786432;
    u16* bqkv  = wseg + 1048576;
    u16* bproj = wseg + 1050112;
    u16* rpbc  = wseg + 1050624;
    u16* xc    = ws + 16 + 1050880;                  // 2*lch*512
    u16* qkv   = xc + (size_t)1024 * lch;            // 3 planes of 1024*lch
    u16* wsa   = qkv + (size_t)3072 * lch;           // 2*lc*512

    convert_weights_kernel<<<2048, 256, 0, stream>>>(qkv_w, proj_w, qkv_b, proj_b,
                                                     rpb, wseg, (const u16*)x, flag);

    for (int c = 0; c < nchunk; c++) {
        convert_x_kernel<<<lch / 2, 256, 0, stream>>>(x, xc, bases[c], lch, flag);
        gemm_qkv_kernel<<<dim3(lch / 256, 6, 2), 512, 0, stream>>>(
            xc, wqkv, bqkv, qkv, lch);
        attn_kernel<<<lc / 2, 256, 0, stream>>>(
            (const uint4*)qkv, (const uint4*)(qkv + (size_t)1024 * lch),
            (const uint4*)(qkv + (size_t)2048 * lch), rpbc,
            (uint4*)wsa, c0s[c], bases[c], lc_shift, lch);
        gemm_proj_kernel<<<dim3(lc / 256, 2, 2), 512, 0, stream>>>(
            wsa, wproj, bproj, d_out, c0s[c], lc, flag);
    }
}